// Round 7
// baseline (707.233 us; speedup 1.0000x reference)
//
#include <hip/hip_runtime.h>
#include <math.h>

#define N_NODES 50000
#define N_EDGES 1600000
#define D 128
#define BN_EPS 1e-5f

#define NSLICE 8
#define SLICE_NODES 6250        // divides 50000 exactly
#define SUBB 24                 // slots per (node, src-slice); Poisson(4), P(>=24)~8e-12
#define ROWL (NSLICE * SUBB)    // 192 u16 per node = 384 B
#define NREP 64                 // BN partial-sum replicas
#define NBLK_P 1000             // partition blocks
#define CHUNK 1600              // edges per partition block (1000*1600 = 1.6M exact)
#define SEGCAP 320              // per (bin, block) segment capacity; Binom(1600,1/8) ~ 200 +- 13

typedef __attribute__((ext_vector_type(8))) short short8;
typedef __attribute__((ext_vector_type(8))) unsigned short ushort8v;
typedef __attribute__((ext_vector_type(4))) float f32x4;

// bf16 helpers (manual, RNE)
__device__ __forceinline__ unsigned short f2bf(float f) {
    unsigned u = __float_as_uint(f);
    u += 0x7FFFu + ((u >> 16) & 1u);
    return (unsigned short)(u >> 16);
}
__device__ __forceinline__ float bf2f(unsigned short u) {
    return __uint_as_float(((unsigned)u) << 16);
}

// ============================================================
// Phase 1: partition edges into block-private per-dst-slice segments.
// Wave-ballot binning: 8 ballots + 1 LDS atomic per wave per bin, NO
// per-chunk barriers (round-5 partition's failure mode). Writes are
// per-wave bursts into private segments -> near-sequential.
// code = (dst_local << 16) | src   (dst_local < 6250, src < 50000)
// ============================================================
__global__ __launch_bounds__(256) void partition_edges_kernel(const int* __restrict__ src,
                                                              const int* __restrict__ dst,
                                                              unsigned int* __restrict__ part,
                                                              unsigned int* __restrict__ pcnt) {
    __shared__ unsigned int lcnt[NSLICE];
    int tid = threadIdx.x, lane = tid & 63;
    int blk = blockIdx.x;
    if (tid < NSLICE) lcnt[tid] = 0;
    __syncthreads();
    int base = blk * CHUNK;
#pragma unroll 1
    for (int it = 0; it < (CHUNK + 255) / 256; it++) {
        int e = base + it * 256 + tid;
        bool valid = (e < base + CHUNK);
        int bin = 0; unsigned code = 0;
        if (valid) {
            int d = dst[e], s = src[e];
            bin = d / SLICE_NODES;
            code = ((unsigned)(d - bin * SLICE_NODES) << 16) | (unsigned)s;
        }
        int slot = -1;
#pragma unroll
        for (int b = 0; b < NSLICE; b++) {
            unsigned long long m = __ballot(valid && bin == b);
            if (valid && bin == b) {
                int rank = __popcll(m & ((1ull << lane) - 1ull));
                int leader = __ffsll((unsigned long long)m) - 1;
                unsigned wbase = 0;
                if (lane == leader) wbase = atomicAdd(&lcnt[b], (unsigned)__popcll(m));
                wbase = (unsigned)__shfl((int)wbase, leader, 64);
                slot = (int)(wbase + rank);
            }
        }
        if (valid && slot < SEGCAP)
            part[((size_t)bin * NBLK_P + blk) * SEGCAP + slot] = code;
    }
    __syncthreads();
    if (tid < NSLICE) pcnt[blk * NSLICE + tid] = lcnt[tid] > SEGCAP ? SEGCAP : lcnt[tid];
}

// ============================================================
// Phase 2: slice-local scatter into sub-bucketed u16 CSR.
// blockIdx&7 -> XCD affinity; reads = 10 KB of L2-hot segments per
// block; 2 dst-half sub-passes -> 1.2 MB write window per pass.
// csr[d][t][pos], t = src-slice (gives gather its phase locality).
// ============================================================
__global__ __launch_bounds__(256) void scatter_csr_kernel(const unsigned int* __restrict__ part,
                                                          const unsigned int* __restrict__ pcnt,
                                                          unsigned int* __restrict__ cnt8,
                                                          unsigned short* __restrict__ csr) {
    int slice = blockIdx.x & (NSLICE - 1);
    int sb = blockIdx.x >> 3;            // 0..127 team index within slice
    int nodebase = slice * SLICE_NODES;
    int sg0 = sb * 8;
    int sg1 = sg0 + 8; if (sg1 > NBLK_P) sg1 = NBLK_P;
#pragma unroll 1
    for (int h = 0; h < 2; h++) {        // dst halves: dl<3125 then dl>=3125
        for (int sg = sg0; sg < sg1; sg++) {
            unsigned n = pcnt[sg * NSLICE + slice];
            const unsigned* seg = &part[((size_t)slice * NBLK_P + sg) * SEGCAP];
            for (unsigned i = threadIdx.x; i < n; i += 256) {
                unsigned code = seg[i];
                int dl = (int)(code >> 16);
                if ((dl >= SLICE_NODES / 2) == h) {
                    int s = (int)(code & 0xFFFFu);
                    int t = s / SLICE_NODES;
                    int d = nodebase + dl;
                    unsigned pos = atomicAdd(&cnt8[(d << 3) + t], 1u);
                    if (pos < SUBB) csr[(size_t)d * ROWL + t * SUBB + pos] = (unsigned short)s;
                }
            }
        }
    }
}

__global__ void compute_dinv_kernel(const unsigned int* __restrict__ cnt8, float* __restrict__ dinv) {
    int n = blockIdx.x * blockDim.x + threadIdx.x;
    if (n < N_NODES) {
        const uint4* c = (const uint4*)&cnt8[n << 3];
        uint4 a = c[0], b = c[1];
        unsigned deg = a.x + a.y + a.z + a.w + b.x + b.y + b.z + b.w;  // raw deg (matches ref)
        dinv[n] = rsqrtf((float)deg + 2.0f);   // improved=True: self-loop weight 2
    }
}

// ============================================================
// Per-layer weight prep: Wt[n][k] = bf16(W[k][n]), 3 layers, 3 blocks.
// ============================================================
__global__ void prep_weights_kernel(const float* __restrict__ W0, const float* __restrict__ W1,
                                    const float* __restrict__ W2, unsigned short* __restrict__ Wt) {
    const float* W = (blockIdx.x == 0) ? W0 : (blockIdx.x == 1) ? W1 : W2;
    unsigned short* o = Wt + (size_t)blockIdx.x * D * D;
    int t = threadIdx.x;        // 256
    int n = t & 127, half = t >> 7;
    __attribute__((aligned(16))) unsigned short buf[64];
    for (int j = 0; j < 64; j++) {
        int k = half * 64 + j;
        buf[j] = f2bf(W[(size_t)k * D + n]);
    }
    for (int j = 0; j < 64; j += 8)
        *(ushort8v*)&o[(size_t)n * D + half * 64 + j] = *(const ushort8v*)&buf[j];
}

// ============================================================
// MFMA bf16 GEMM + dinv pre-scale: hw'[r,:] = dinv[r] * (act(A[r,:]) @ W)
//   layer 0  (apply_bn=0): A = x (fp32 -> bf16 on the fly)
//   layers 1+ (apply_bn=1): A = agg_bf (bf16), act = relu(a*sc+sh)
// ============================================================
__global__ __launch_bounds__(256) void gemm_mfma_kernel(const float* __restrict__ Af32,
                                                        const unsigned short* __restrict__ Abf,
                                                        const unsigned short* __restrict__ Wt,
                                                        const float* __restrict__ sc_sh,
                                                        const float* __restrict__ dinv,
                                                        int apply_bn,
                                                        unsigned short* __restrict__ outbf) {
    __shared__ unsigned short Cs[4][16][136];
    int tid = threadIdx.x;
    int w = tid >> 6;
    int lane = tid & 63;
    int r = lane & 15, quad = lane >> 4;
    int rowbase = blockIdx.x * 64 + w * 16;
    int arow = rowbase + r;
    int arowc = (arow < N_NODES) ? arow : 0;

    f32x4 acc[8] = {};
#pragma unroll
    for (int kc = 0; kc < 128; kc += 32) {
        int ko = kc + quad * 8;
        short8 a;
        if (apply_bn) {
            short8 araw = *(const short8*)&Abf[(size_t)arowc * D + ko];
            const float* sc = &sc_sh[ko];
            const float* sh = &sc_sh[128 + ko];
#pragma unroll
            for (int j = 0; j < 8; j++) {
                float v = bf2f((unsigned short)araw[j]);
                v = fmaxf(fmaf(v, sc[j], sh[j]), 0.f);
                a[j] = (short)f2bf(v);
            }
        } else {
            float4 v0 = *(const float4*)&Af32[(size_t)arowc * D + ko];
            float4 v1 = *(const float4*)&Af32[(size_t)arowc * D + ko + 4];
            a[0] = (short)f2bf(v0.x); a[1] = (short)f2bf(v0.y);
            a[2] = (short)f2bf(v0.z); a[3] = (short)f2bf(v0.w);
            a[4] = (short)f2bf(v1.x); a[5] = (short)f2bf(v1.y);
            a[6] = (short)f2bf(v1.z); a[7] = (short)f2bf(v1.w);
        }
#pragma unroll
        for (int ct = 0; ct < 8; ct++) {
            short8 b = *(const short8*)&Wt[(size_t)(ct * 16 + r) * D + ko];
            acc[ct] = __builtin_amdgcn_mfma_f32_16x16x32_bf16(a, b, acc[ct], 0, 0, 0);
        }
    }
    float4 d4 = *(const float4*)&dinv[rowbase + quad * 4];  // dinv padded past N
    float dv[4] = {d4.x, d4.y, d4.z, d4.w};
#pragma unroll
    for (int ct = 0; ct < 8; ct++)
#pragma unroll
        for (int i = 0; i < 4; i++)
            Cs[w][quad * 4 + i][ct * 16 + r] = f2bf(acc[ct][i] * dv[i]);

    int r2 = lane >> 2;   // 0..15
    int seg = lane & 3;   // 0..3, 32 cols each
    int orow = rowbase + r2;
    if (orow < N_NODES) {
#pragma unroll
        for (int jj = 0; jj < 4; jj++) {
            *(ushort8v*)&outbf[(size_t)orow * D + seg * 32 + jj * 8] =
                *(const ushort8v*)&Cs[w][r2][seg * 32 + jj * 8];
        }
    }
}

// ============================================================
// Fused gather + BN-stats. hw is dinv-pre-scaled:
//   agg[g] = dinv[g] * ( sum_e hw'[src_e] + 2*hw'[g] )
// ONE 64-lane wave per node (lane owns 2 cols, 4B): no intra-wave
// divergence; indices read 8-at-a-time via wave-uniform 16B broadcast
// load (no shfl / LDS pipe) -> 8 independent row loads in flight.
// Sub-buckets swept slice 0..7 in phase -> 1.6 MB concurrent window.
// ============================================================
__global__ __launch_bounds__(256) void gather_agg_stats_kernel(const unsigned short* __restrict__ hw,
                                                               const unsigned short* __restrict__ csr,
                                                               const unsigned int* __restrict__ cnt8,
                                                               const float* __restrict__ dinv,
                                                               unsigned short* __restrict__ out,
                                                               float* __restrict__ rep) {
    __shared__ float pS[4][128];
    __shared__ float pQ[4][128];
    int w = threadIdx.x >> 6, lane = threadIdx.x & 63;
    int g = blockIdx.x * 4 + w;          // 12500 * 4 = 50000 exact
    const unsigned* hwv = (const unsigned*)hw;   // 4B = 2 bf16 (lo u16 = even col)
    float di = dinv[g];
    unsigned su = hwv[(size_t)g * 64 + lane];
    float ax = 2.f * __uint_as_float(su << 16);
    float ay = 2.f * __uint_as_float(su & 0xFFFF0000u);
    const unsigned short* row = csr + (size_t)g * ROWL;
#pragma unroll 1
    for (int t = 0; t < NSLICE; t++) {
        int dt = (int)cnt8[(g << 3) + t];        // wave-uniform broadcast load
        if (dt > SUBB) dt = SUBB;
        const unsigned short* sub = row + t * SUBB;
#pragma unroll 1
        for (int j0 = 0; j0 < dt; j0 += 8) {
            ushort8v idx8 = *(const ushort8v*)&sub[j0];   // 16B broadcast (aligned: 48B*t+16B*j0/8)
            int m = dt - j0; if (m > 8) m = 8;
#pragma unroll
            for (int j = 0; j < 8; j++) {
                if (j < m) {
                    int sj = (int)(unsigned short)idx8[j];
                    unsigned u = hwv[(size_t)sj * 64 + lane];
                    ax += __uint_as_float(u << 16);
                    ay += __uint_as_float(u & 0xFFFF0000u);
                }
            }
        }
    }
    ax *= di; ay *= di;
    unsigned o = (unsigned)f2bf(ax) | ((unsigned)f2bf(ay) << 16);
    ((unsigned*)out)[(size_t)g * 64 + lane] = o;

    // BN partials: cols 2*lane, 2*lane+1
    pS[w][2 * lane] = ax;  pS[w][2 * lane + 1] = ay;
    pQ[w][2 * lane] = ax * ax;  pQ[w][2 * lane + 1] = ay * ay;
    __syncthreads();
    int c = threadIdx.x & 127;
    int rbase = (blockIdx.x & (NREP - 1)) * 256;
    if (threadIdx.x < 128) {
        float tot = pS[0][c] + pS[1][c] + pS[2][c] + pS[3][c];
        atomicAdd(&rep[rbase + c], tot);
    } else {
        float tot = pQ[0][c] + pQ[1][c] + pQ[2][c] + pQ[3][c];
        atomicAdd(&rep[rbase + 128 + c], tot);
    }
}

// ============================================================
// Reduce NREP replicas -> sc/sh; re-zero replicas for next layer.
// ============================================================
__global__ void bn_reduce_finalize_kernel(const float* __restrict__ gamma,
                                          const float* __restrict__ beta,
                                          float* __restrict__ rep,
                                          float* __restrict__ sc_sh) {
    int c = threadIdx.x;
    if (c >= 128) return;
    float s = 0.f, q = 0.f;
#pragma unroll 4
    for (int rr = 0; rr < NREP; rr++) {
        s += rep[rr * 256 + c];
        q += rep[rr * 256 + 128 + c];
        rep[rr * 256 + c] = 0.f;
        rep[rr * 256 + 128 + c] = 0.f;
    }
    float inv_n = 1.0f / (float)N_NODES;
    float mean = s * inv_n;
    float var = q * inv_n - mean * mean;
    float inv = rsqrtf(var + BN_EPS);
    float sc = gamma[c] * inv;
    sc_sh[c] = sc;
    sc_sh[128 + c] = beta[c] - mean * sc;
}

// final layer: bf16 agg -> BN+ReLU -> fp32 d_out
__global__ void bn_apply_kernel(const unsigned short* __restrict__ h,
                                const float* __restrict__ sc_sh,
                                float* __restrict__ out) {
    int i = blockIdx.x * blockDim.x + threadIdx.x;
    int stride = gridDim.x * blockDim.x;
    const int total = N_NODES * 32;  // 4-elem groups
    for (; i < total; i += stride) {
        int cg = i & 31;
        ushort4 u = ((const ushort4*)h)[i];
        float4 sc = ((const float4*)sc_sh)[cg];
        float4 sh = ((const float4*)sc_sh)[32 + cg];
        float4 v;
        v.x = fmaxf(fmaf(bf2f(u.x), sc.x, sh.x), 0.f);
        v.y = fmaxf(fmaf(bf2f(u.y), sc.y, sh.y), 0.f);
        v.z = fmaxf(fmaf(bf2f(u.z), sc.z, sh.z), 0.f);
        v.w = fmaxf(fmaf(bf2f(u.w), sc.w, sh.w), 0.f);
        ((float4*)out)[i] = v;
    }
}

// ============================================================
// Launch
// ============================================================
extern "C" void kernel_launch(void* const* d_in, const int* in_sizes, int n_in,
                              void* d_out, int out_size, void* d_ws, size_t ws_size,
                              hipStream_t stream) {
    const float* x = (const float*)d_in[0];
    const int* ei = (const int*)d_in[1];
    const int* src = ei;
    const int* dst = ei + N_EDGES;
    const float* Wm[3] = {(const float*)d_in[2], (const float*)d_in[6], (const float*)d_in[10]};
    const float* gm[3] = {(const float*)d_in[4], (const float*)d_in[8], (const float*)d_in[12]};
    const float* bm[3] = {(const float*)d_in[5], (const float*)d_in[9], (const float*)d_in[13]};

    char* p = (char*)d_ws;
    auto carve = [&](size_t bytes) { char* r = p; p += (bytes + 255) & ~(size_t)255; return r; };
    unsigned short* hwB    = (unsigned short*)carve((size_t)N_NODES * D * sizeof(unsigned short));
    unsigned short* aggbf  = (unsigned short*)carve((size_t)N_NODES * D * sizeof(unsigned short));
    unsigned short* Wt     = (unsigned short*)carve((size_t)3 * D * D * sizeof(unsigned short));
    float*          dinv   = (float*)carve((N_NODES + 64) * sizeof(float));
    unsigned int*   cnt8   = (unsigned int*)carve((size_t)(N_NODES * 8 + NREP * 256) * sizeof(unsigned int));
    float*          rep    = (float*)(cnt8 + (size_t)N_NODES * 8);
    unsigned int*   part   = (unsigned int*)carve((size_t)NSLICE * NBLK_P * SEGCAP * sizeof(unsigned int));
    unsigned int*   pcnt   = (unsigned int*)carve((size_t)NBLK_P * NSLICE * sizeof(unsigned int));
    unsigned short* csr    = (unsigned short*)carve((size_t)N_NODES * ROWL * sizeof(unsigned short));
    float*          sc_sh  = (float*)carve(256 * sizeof(float));

    // ---- graph prep: ballot-partition + L2-local scatter ----
    hipMemsetAsync(cnt8, 0, (size_t)(N_NODES * 8 + NREP * 256) * sizeof(unsigned int), stream);
    partition_edges_kernel<<<NBLK_P, 256, 0, stream>>>(src, dst, part, pcnt);
    scatter_csr_kernel<<<1024, 256, 0, stream>>>(part, pcnt, cnt8, csr);
    compute_dinv_kernel<<<(N_NODES + 255) / 256, 256, 0, stream>>>(cnt8, dinv);
    prep_weights_kernel<<<3, 256, 0, stream>>>(Wm[0], Wm[1], Wm[2], Wt);

    // ---- 3 GCN layers; BN-apply of layers 0,1 fused into next GEMM ----
    const unsigned short* Ain = nullptr;
    for (int l = 0; l < 3; l++) {
        gemm_mfma_kernel<<<(N_NODES + 63) / 64, 256, 0, stream>>>(
            x, Ain, Wt + (size_t)l * D * D, sc_sh, dinv, l > 0 ? 1 : 0, hwB);
        gather_agg_stats_kernel<<<N_NODES / 4, 256, 0, stream>>>(hwB, csr, cnt8, dinv, aggbf, rep);
        bn_reduce_finalize_kernel<<<1, 128, 0, stream>>>(gm[l], bm[l], rep, sc_sh);
        Ain = aggbf;
    }
    bn_apply_kernel<<<2048, 256, 0, stream>>>(aggbf, sc_sh, (float*)d_out);
}